// Round 3
// baseline (223.462 us; speedup 1.0000x reference)
//
#include <hip/hip_runtime.h>
#include <hip/hip_bf16.h>
#include <stdint.h>

// ---------------- problem constants ----------------
#define NB   32
#define NC   256
#define NOC  256
#define HWD  56
#define NPIX 3136      // 56*56
#define PW   58        // padded row width
#define PPIX 3364      // 58*58
#define KTOT 2304      // 9 * 256
#define MOD  512       // fc1 out channels
#define GAPD 16

// workspace layout (bytes)
#define XBT_BYTES ((size_t)NB * PPIX * NC * 2)            // 55,115,776
#define WA_BYTES  ((size_t)NB * NOC * KTOT * 2)           // 37,748,736

typedef __bf16 bf16x8 __attribute__((ext_vector_type(8)));
typedef float  f32x4  __attribute__((ext_vector_type(4)));
typedef unsigned short u16x8 __attribute__((ext_vector_type(8)));

__device__ __forceinline__ unsigned short f2bf(float f) {
    union { float f; unsigned int u; } v; v.f = f;
    unsigned int u = v.u;
    return (unsigned short)((u + 0x7FFFu + ((u >> 16) & 1u)) >> 16);
}

// ---------------- P1: SE network (one block, 512 threads) ----------------
__global__ void se_kernel(const float* __restrict__ gap,
                          const float* __restrict__ rw, const float* __restrict__ rb,
                          const float* __restrict__ f1w, float* __restrict__ a2) {
    __shared__ float sgap[NB * NC];
    __shared__ float sg[NB * GAPD];
    int t = threadIdx.x; // 0..511
    #pragma unroll
    for (int i = 0; i < 16; ++i) sgap[i * 512 + t] = gap[i * 512 + t];
    __syncthreads();
    {
        int b = t >> 4, tt = t & 15;
        float s = rb[tt];
        for (int c = 0; c < NC; ++c) s += sgap[b * NC + c] * rw[tt * NC + c];
        sg[b * GAPD + tt] = s;
    }
    __syncthreads();
    for (int i = 0; i < 32; ++i) {
        int o = i * 512 + t;
        int b = o >> 9, m = o & 511;
        float s = 0.f;
        #pragma unroll
        for (int tt = 0; tt < GAPD; ++tt) s += sg[b * GAPD + tt] * f1w[m * GAPD + tt];
        a2[o] = 1.0f / (1.0f + __expf(-s));
    }
}

// ---------------- P2: per-batch conv weights, bf16, k = s*256+c ----------------
// LDS-staged fc2 row: coalesced float4 global loads, conflict-free LDS reads
__global__ void wk_kernel(const float* __restrict__ a2,
                          const float* __restrict__ f2w, const float* __restrict__ f2b,
                          unsigned short* __restrict__ wa) {
    __shared__ float sw[KTOT];
    __shared__ float sbv[KTOT];
    int oc = blockIdx.x, b = blockIdx.y, c = threadIdx.x;
    const float4* wsrc = (const float4*)(f2w + (size_t)oc * KTOT);
    const float4* bsrc = (const float4*)(f2b + (size_t)oc * KTOT);
    #pragma unroll
    for (int i = 0; i < 3; ++i) {
        int idx = i * 256 + c;
        if (idx < 576) {
            float4 wv = wsrc[idx], bv = bsrc[idx];
            ((float4*)sw)[idx] = wv;
            ((float4*)sbv)[idx] = bv;
        }
    }
    float a0 = a2[b * MOD + 2 * oc];
    float a1 = a2[b * MOD + 2 * oc + 1];
    __syncthreads();
    unsigned short* dst = wa + (size_t)(b * NOC + oc) * KTOT;
    #pragma unroll
    for (int s = 0; s < 9; ++s) {
        int rem = c * 9 + s;
        float a = (rem >= 1152) ? a1 : a0;
        float v = a * sw[rem] + sbv[rem];
        dst[s * NC + c] = f2bf(v);
    }
}

// ---------------- P3: zero the halo of xbt ----------------
__global__ void halo_kernel(unsigned short* __restrict__ xbt) {
    int b = blockIdx.x, t = threadIdx.x;
    unsigned short* xb = xbt + (size_t)b * PPIX * NC;
    u16x8 z = {};
    for (int i = t; i < 3712; i += 256) {
        int r = (i >= 1856) ? 1 : 0;
        int c = i - r * 1856;
        int pix = r * (57 * 58) + (c >> 5);
        *(u16x8*)(xb + (size_t)pix * NC + (c & 31) * 8) = z;
    }
    for (int i = t; i < 3584; i += 256) {
        int row = 1 + (i >> 6);
        int side = (i >> 5) & 1;
        int pix = row * PW + side * 57;
        *(u16x8*)(xb + (size_t)pix * NC + (i & 31) * 8) = z;
    }
}

// ---------------- P4: x -> bf16 NHWC with halo, fused GAP partial sums ----------------
#define TSTR 59
__global__ void xpose_kernel(const float* __restrict__ x, unsigned short* __restrict__ xbt,
                             float* __restrict__ gap) {
    __shared__ unsigned short tile[NC * TSTR];
    int py = blockIdx.x, b = blockIdx.y, t = threadIdx.x;
    int wv = t >> 6, l = t & 63;
    const float* xs = x + (size_t)b * NC * NPIX + py * HWD;
    // load phase: float4-coalesced; wave wv covers rows wv*64..wv*64+63
    int q = l & 15;            // f4 index within row (0..13 valid)
    int rb4 = l >> 4;          // row within 4-row group
    #pragma unroll
    for (int it = 0; it < 16; ++it) {
        int c = wv * 64 + it * 4 + rb4;
        if (q < 14) {
            float4 v = *(const float4*)(xs + (size_t)c * NPIX + q * 4);
            unsigned short* tr = tile + c * TSTR + q * 4;
            tr[0] = f2bf(v.x); tr[1] = f2bf(v.y); tr[2] = f2bf(v.z); tr[3] = f2bf(v.w);
        }
    }
    __syncthreads();
    // fused GAP: thread t = channel t sums its row of this py-slice
    {
        float s = 0.f;
        #pragma unroll
        for (int px = 0; px < 56; ++px) {
            union { unsigned int u; float f; } cv;
            cv.u = ((unsigned int)tile[t * TSTR + px]) << 16;
            s += cv.f;
        }
        atomicAdd(&gap[b * NC + t], s * (1.0f / NPIX));
    }
    int cch = t & 31, pg = t >> 5;
    for (int i = 0; i < 7; ++i) {
        int px = pg * 7 + i;
        u16x8 v;
        #pragma unroll
        for (int j = 0; j < 8; ++j) v[j] = tile[(cch * 8 + j) * TSTR + px];
        *(u16x8*)(xbt + ((size_t)b * PPIX + (size_t)(1 + py) * PW + 1 + px) * NC + cch * 8) = v;
    }
}

// ---------------- main GEMM: 256x256 tile, 4 waves (128x128 each), 4-slice pipeline ----------------
// K = 2304 = 72 phases of 32. Slice = A[256][32] + B[256][32] = 32 KB. 128 KB LDS.
// 8 global_load_lds per thread per slice; prefetch distance 2 -> vmcnt(16).
#define SLICE_BYTES 32768
#define B_OFF 16384

#define PWAIT(N) do { asm volatile("s_waitcnt vmcnt(" #N ")" ::: "memory"); \
    __builtin_amdgcn_s_barrier(); __builtin_amdgcn_sched_barrier(0); } while (0)

__global__ __launch_bounds__(256, 1) void conv_gemm(
    const unsigned short* __restrict__ wa,   // [32][256][2304] bf16
    const unsigned short* __restrict__ xbt,  // [32][3364][256] bf16 (padded NHWC)
    float* __restrict__ out)                 // [32][256][3136]
{
    __shared__ __attribute__((aligned(16))) char lds[4 * SLICE_BYTES];  // 128 KB

    // XCD-aware bijective swizzle: 416 blocks = 8 XCD * 52; 4 whole batches per XCD
    const int bid = blockIdx.x;
    const int wg  = (bid & 7) * 52 + (bid >> 3);
    const int nt  = wg % 13, b = wg / 13;

    const int t = threadIdx.x;
    const int w = t >> 6, l = t & 63;            // 4 waves
    const int wm = w >> 1, wn = w & 1;           // 2M x 2N, each 128x128

    const unsigned short* waB = wa + (size_t)b * NOC * KTOT;
    const unsigned short* xbB = xbt + (size_t)b * PPIX * NC;

    // staging: unit u (1KB) = rows u*16..+15, 4 chunks of 16B, source pre-swizzled
    // lane l -> row l>>2, phys chunk l&3, logical chunk q = (l&3)^((l>>3)&3)
    const int srow = l >> 2;
    const int sq   = (l & 3) ^ ((l >> 3) & 3);
    // issue round i in 0..3: wave w stages A unit (4i+w) = rows 64i + w*16 + srow
    const unsigned short* pA[4];
    const unsigned short* pB[4];
    #pragma unroll
    for (int i = 0; i < 4; ++i) {
        int m = i * 64 + w * 16 + srow;
        pA[i] = waB + (size_t)m * KTOT + sq * 8;
        int pg = nt * 256 + m; if (pg > NPIX - 1) pg = NPIX - 1;
        int py = pg / 56, px = pg - py * 56;
        pB[i] = xbB + (size_t)((py + 1) * PW + (px + 1)) * NC + sq * 8;
    }

    f32x4 acc[8][8] = {};

    auto issue = [&](int tp) {
        char* sb = lds + (tp & 3) * SLICE_BYTES;
        const int koff = tp * 32;
        const int s9 = tp >> 3;
        const int dy = s9 / 3, dx = s9 - dy * 3;
        const int bsh = ((dy - 1) * PW + (dx - 1)) * NC + (tp & 7) * 32;
        #pragma unroll
        for (int i = 0; i < 4; ++i)
            __builtin_amdgcn_global_load_lds(
                (const __attribute__((address_space(1))) void*)(pA[i] + koff),
                (__attribute__((address_space(3))) void*)(sb + (i * 4 + w) * 1024), 16, 0, 0);
        #pragma unroll
        for (int i = 0; i < 4; ++i)
            __builtin_amdgcn_global_load_lds(
                (const __attribute__((address_space(1))) void*)(pB[i] + bsh),
                (__attribute__((address_space(3))) void*)(sb + B_OFF + (i * 4 + w) * 1024), 16, 0, 0);
    };

    // read: row r, logical chunk kq at phys kq ^ ((r>>1)&3); lane-constant offset
    const int physq16 = (((l >> 4) ^ ((l >> 1) & 3)) << 4);
    const int arow = (l & 15) << 6;

    auto compute = [&](int p) {
        const char* sb = lds + (p & 3) * SLICE_BYTES;
        bf16x8 af[8], bfr[8];
        #pragma unroll
        for (int i = 0; i < 8; ++i)
            af[i] = *(const bf16x8*)(sb + wm * 8192 + i * 1024 + arow + physq16);
        #pragma unroll
        for (int j = 0; j < 8; ++j)
            bfr[j] = *(const bf16x8*)(sb + B_OFF + wn * 8192 + j * 1024 + arow + physq16);
        __builtin_amdgcn_s_setprio(1);
        #pragma unroll
        for (int i = 0; i < 8; ++i)
            #pragma unroll
            for (int j = 0; j < 8; ++j)
                acc[i][j] = __builtin_amdgcn_mfma_f32_16x16x32_bf16(af[i], bfr[j], acc[i][j], 0, 0, 0);
        __builtin_amdgcn_s_setprio(0);
    };

    issue(0); issue(1);
    #pragma unroll 4
    for (int p = 0; p < 68; ++p) { issue(p + 2); PWAIT(16); compute(p); }
    issue(70); PWAIT(16); compute(68);
    issue(71); PWAIT(16); compute(69);
    PWAIT(8);  compute(70);
    PWAIT(0);  compute(71);

    // epilogue: D lane map col = l&15 (pixel), row = (l>>4)*4 + r (oc)
    const int ocb = wm * 128 + ((l >> 4) << 2);
    const int pxb = nt * 256 + wn * 128 + (l & 15);
    #pragma unroll
    for (int i = 0; i < 8; ++i) {
        #pragma unroll
        for (int j = 0; j < 8; ++j) {
            int p = pxb + j * 16;
            if (p < NPIX) {
                float* o = out + ((size_t)(b * NOC + ocb + i * 16)) * NPIX + p;
                o[0]        = acc[i][j][0];
                o[NPIX]     = acc[i][j][1];
                o[2 * NPIX] = acc[i][j][2];
                o[3 * NPIX] = acc[i][j][3];
            }
        }
    }
}

extern "C" void kernel_launch(void* const* d_in, const int* in_sizes, int n_in,
                              void* d_out, int out_size, void* d_ws, size_t ws_size,
                              hipStream_t stream) {
    (void)in_sizes; (void)n_in; (void)out_size; (void)ws_size;
    const float* x   = (const float*)d_in[0];
    const float* rw  = (const float*)d_in[1];
    const float* rb  = (const float*)d_in[2];
    const float* f1w = (const float*)d_in[3];
    const float* f2w = (const float*)d_in[4];
    const float* f2b = (const float*)d_in[5];
    float* out = (float*)d_out;

    char* wsb = (char*)d_ws;
    unsigned short* xbt = (unsigned short*)wsb;
    unsigned short* wa  = (unsigned short*)(wsb + XBT_BYTES);
    float* gap = (float*)(wsb + XBT_BYTES + WA_BYTES);
    float* a2  = (float*)(wsb + XBT_BYTES + WA_BYTES + (size_t)NB * NC * 4);

    hipMemsetAsync(gap, 0, (size_t)NB * NC * 4, stream);
    halo_kernel<<<dim3(32), 256, 0, stream>>>(xbt);
    xpose_kernel<<<dim3(56, 32), 256, 0, stream>>>(x, xbt, gap);
    se_kernel<<<dim3(1), 512, 0, stream>>>(gap, rw, rb, f1w, a2);
    wk_kernel<<<dim3(256, 32), 256, 0, stream>>>(a2, f2w, f2b, wa);
    conv_gemm<<<dim3(416), 256, 0, stream>>>(wa, xbt, out);
}

// Round 4
// 208.377 us; speedup vs baseline: 1.0724x; 1.0724x over previous
//
#include <hip/hip_runtime.h>
#include <hip/hip_bf16.h>
#include <stdint.h>

// ---------------- problem constants ----------------
#define NB   32
#define NC   256
#define NOC  256
#define HWD  56
#define NPIX 3136      // 56*56
#define PW   58        // padded row width
#define PPIX 3364      // 58*58
#define KTOT 2304      // 9 * 256
#define MOD  512       // fc1 out channels
#define GAPD 16

// workspace layout (bytes)
#define XBT_BYTES ((size_t)NB * PPIX * NC * 2)            // 55,115,776
#define WA_BYTES  ((size_t)NB * NOC * KTOT * 2)           // 37,748,736

typedef __bf16 bf16x8 __attribute__((ext_vector_type(8)));
typedef float  f32x4  __attribute__((ext_vector_type(4)));
typedef unsigned short u16x8 __attribute__((ext_vector_type(8)));

__device__ __forceinline__ unsigned short f2bf(float f) {
    union { float f; unsigned int u; } v; v.f = f;
    unsigned int u = v.u;
    return (unsigned short)((u + 0x7FFFu + ((u >> 16) & 1u)) >> 16);
}

// ---------------- P1: SE network (one block, 512 threads) ----------------
__global__ void se_kernel(const float* __restrict__ gap,
                          const float* __restrict__ rw, const float* __restrict__ rb,
                          const float* __restrict__ f1w, float* __restrict__ a2) {
    __shared__ float sgap[NB * NC];
    __shared__ float sg[NB * GAPD];
    int t = threadIdx.x; // 0..511
    #pragma unroll
    for (int i = 0; i < 16; ++i) sgap[i * 512 + t] = gap[i * 512 + t];
    __syncthreads();
    {
        int b = t >> 4, tt = t & 15;
        float s = rb[tt];
        for (int c = 0; c < NC; ++c) s += sgap[b * NC + c] * rw[tt * NC + c];
        sg[b * GAPD + tt] = s;
    }
    __syncthreads();
    for (int i = 0; i < 32; ++i) {
        int o = i * 512 + t;
        int b = o >> 9, m = o & 511;
        float s = 0.f;
        #pragma unroll
        for (int tt = 0; tt < GAPD; ++tt) s += sg[b * GAPD + tt] * f1w[m * GAPD + tt];
        a2[o] = 1.0f / (1.0f + __expf(-s));
    }
}

// ---------------- P2: per-batch conv weights, bf16, k = s*256+c ----------------
__global__ void wk_kernel(const float* __restrict__ a2,
                          const float* __restrict__ f2w, const float* __restrict__ f2b,
                          unsigned short* __restrict__ wa) {
    __shared__ float sw[KTOT];
    __shared__ float sbv[KTOT];
    int oc = blockIdx.x, b = blockIdx.y, c = threadIdx.x;
    const float4* wsrc = (const float4*)(f2w + (size_t)oc * KTOT);
    const float4* bsrc = (const float4*)(f2b + (size_t)oc * KTOT);
    #pragma unroll
    for (int i = 0; i < 3; ++i) {
        int idx = i * 256 + c;
        if (idx < 576) {
            float4 wv = wsrc[idx], bv = bsrc[idx];
            ((float4*)sw)[idx] = wv;
            ((float4*)sbv)[idx] = bv;
        }
    }
    float a0 = a2[b * MOD + 2 * oc];
    float a1 = a2[b * MOD + 2 * oc + 1];
    __syncthreads();
    unsigned short* dst = wa + (size_t)(b * NOC + oc) * KTOT;
    #pragma unroll
    for (int s = 0; s < 9; ++s) {
        int rem = c * 9 + s;
        float a = (rem >= 1152) ? a1 : a0;
        float v = a * sw[rem] + sbv[rem];
        dst[s * NC + c] = f2bf(v);
    }
}

// ---------------- P3: zero the halo of xbt ----------------
__global__ void halo_kernel(unsigned short* __restrict__ xbt) {
    int b = blockIdx.x, t = threadIdx.x;
    unsigned short* xb = xbt + (size_t)b * PPIX * NC;
    u16x8 z = {};
    for (int i = t; i < 3712; i += 256) {
        int r = (i >= 1856) ? 1 : 0;
        int c = i - r * 1856;
        int pix = r * (57 * 58) + (c >> 5);
        *(u16x8*)(xb + (size_t)pix * NC + (c & 31) * 8) = z;
    }
    for (int i = t; i < 3584; i += 256) {
        int row = 1 + (i >> 6);
        int side = (i >> 5) & 1;
        int pix = row * PW + side * 57;
        *(u16x8*)(xb + (size_t)pix * NC + (i & 31) * 8) = z;
    }
}

// ---------------- P4: x -> bf16 NHWC with halo, fused GAP partial sums ----------------
#define TSTR 59
__global__ void xpose_kernel(const float* __restrict__ x, unsigned short* __restrict__ xbt,
                             float* __restrict__ gap) {
    __shared__ unsigned short tile[NC * TSTR];
    int py = blockIdx.x, b = blockIdx.y, t = threadIdx.x;
    int wv = t >> 6, l = t & 63;
    const float* xs = x + (size_t)b * NC * NPIX + py * HWD;
    int q = l & 15;
    int rb4 = l >> 4;
    #pragma unroll
    for (int it = 0; it < 16; ++it) {
        int c = wv * 64 + it * 4 + rb4;
        if (q < 14) {
            float4 v = *(const float4*)(xs + (size_t)c * NPIX + q * 4);
            unsigned short* tr = tile + c * TSTR + q * 4;
            tr[0] = f2bf(v.x); tr[1] = f2bf(v.y); tr[2] = f2bf(v.z); tr[3] = f2bf(v.w);
        }
    }
    __syncthreads();
    {
        float s = 0.f;
        #pragma unroll
        for (int px = 0; px < 56; ++px) {
            union { unsigned int u; float f; } cv;
            cv.u = ((unsigned int)tile[t * TSTR + px]) << 16;
            s += cv.f;
        }
        atomicAdd(&gap[b * NC + t], s * (1.0f / NPIX));
    }
    int cch = t & 31, pg = t >> 5;
    for (int i = 0; i < 7; ++i) {
        int px = pg * 7 + i;
        u16x8 v;
        #pragma unroll
        for (int j = 0; j < 8; ++j) v[j] = tile[(cch * 8 + j) * TSTR + px];
        *(u16x8*)(xbt + ((size_t)b * PPIX + (size_t)(1 + py) * PW + 1 + px) * NC + cch * 8) = v;
    }
}

// ---------------- main GEMM: 256x256 tile, 8 waves, 8-phase ring pipeline ----------------
// K = 2304 = 36 K-tiles of 64; each tile = 4 half-tiles of 16 KB (A0,A1,B0,B1).
// 9-slot LDS ring (144 KB); phase p stages half p+5 (distance 5); counted vmcnt(2)
// at every K-tile boundary (never 0 until the drain).
#define SLOT 16384
#define NSLOT 9
#define NHALF 144       // 36 tiles * 4

__global__ __launch_bounds__(512, 2) void conv_gemm(
    const unsigned short* __restrict__ wa,   // [32][256][2304] bf16
    const unsigned short* __restrict__ xbt,  // [32][3364][256] bf16 (padded NHWC)
    float* __restrict__ out)                 // [32][256][3136]
{
    __shared__ __attribute__((aligned(16))) char lds[NSLOT * SLOT];  // 147456 B

    // XCD-aware bijective swizzle: 416 blocks = 8 XCD * 52; 4 whole batches per XCD
    const int bid = blockIdx.x;
    const int wg  = (bid & 7) * 52 + (bid >> 3);
    const int nt  = wg % 13, b = wg / 13;

    const int t = threadIdx.x;
    const int w = t >> 6, l = t & 63;            // 8 waves
    const int wm = w >> 2, wn = w & 3;           // 2M x 4N, wave tile 128 oc x 64 px

    const unsigned short* waB = wa + (size_t)b * NOC * KTOT;
    const unsigned short* xbB = xbt + (size_t)b * PPIX * NC;

    // ---- staging constants (source pre-swizzle, linear LDS dest) ----
    // half-tile = [128 rows][64 k] bf16, row stride 128 B = 8 chunks of 16 B.
    // thread t stages linear bytes t*16 (row t>>3, physq t&7) and +8192 (row+64).
    // stored logical chunk at physq is physq ^ (row&7).
    const int srow = t >> 3;                    // 0..63
    const int sq8  = ((t & 7) ^ (srow & 7)) * 8; // logical k element offset
    const unsigned short* pA0 = waB + (size_t)srow * KTOT + sq8;
    const unsigned short* pBr[4];
    #pragma unroll
    for (int i = 0; i < 4; ++i) {
        int pg = nt * 256 + i * 64 + srow; if (pg > NPIX - 1) pg = NPIX - 1;
        int py = pg / 56, px = pg - py * 56;
        pBr[i] = xbB + (size_t)((py + 1) * PW + (px + 1)) * NC + sq8;
    }

    // stage half h into ring slot: h -> tile kt=h>>2, type j=h&3
    auto stage = [&](int h, int slot) {
        const int kt = h >> 2, j = h & 3;
        char* sb = lds + slot * SLOT;
        __attribute__((address_space(3))) void* d1 =
            (__attribute__((address_space(3))) void*)(sb + t * 16);
        __attribute__((address_space(3))) void* d2 =
            (__attribute__((address_space(3))) void*)(sb + 8192 + t * 16);
        if (j < 2) {
            const unsigned short* s1 = pA0 + (size_t)(j * 128) * KTOT + kt * 64;
            __builtin_amdgcn_global_load_lds(
                (const __attribute__((address_space(1))) void*)s1, d1, 16, 0, 0);
            __builtin_amdgcn_global_load_lds(
                (const __attribute__((address_space(1))) void*)(s1 + (size_t)64 * KTOT), d2, 16, 0, 0);
        } else {
            const int s9 = kt >> 2;
            const int dy = (s9 >= 6) ? 2 : ((s9 >= 3) ? 1 : 0);
            const int dx = s9 - dy * 3;
            const int bsh = ((dy - 1) * PW + (dx - 1)) * NC + (kt & 3) * 64;
            const unsigned short* s1 = pBr[(j - 2) * 2] + bsh;
            const unsigned short* s2 = pBr[(j - 2) * 2 + 1] + bsh;
            __builtin_amdgcn_global_load_lds(
                (const __attribute__((address_space(1))) void*)s1, d1, 16, 0, 0);
            __builtin_amdgcn_global_load_lds(
                (const __attribute__((address_space(1))) void*)s2, d2, 16, 0, 0);
        }
    };

    // ---- read-side lane constants ----
    // row r = frag*16 + (l&15)  ->  r&7 = l&7 ; chunk kq = kk*4 + (l>>4)
    const int laneA = (l & 15) * 128;
    const int laneQ0 = (((0 * 4 + (l >> 4)) ^ (l & 7)) << 4);
    const int laneQ1 = (((1 * 4 + (l >> 4)) ^ (l & 7)) << 4);

    f32x4 acc[8][4] = {};
    bf16x8 af[8];

    // prologue: stage halves 0..4 into slots 0..4, then wait halves 0..3
    #pragma unroll
    for (int h = 0; h < 5; ++h) stage(h, h);
    asm volatile("s_waitcnt vmcnt(2)" ::: "memory");
    __builtin_amdgcn_s_barrier();
    __builtin_amdgcn_sched_barrier(0);

    int slotC = 0;      // ring slot of half 4T
    int hS = 5;         // next half to stage
    int slotS = 5;

    for (int T = 0; T < 36; ++T) {
        int sA = slotC + wm;             if (sA >= NSLOT) sA -= NSLOT;
        int sB = slotC + 2 + (wn >> 1);  if (sB >= NSLOT) sB -= NSLOT;
        const char* Abase = lds + sA * SLOT + laneA;
        const char* Bbase = lds + sB * SLOT + (wn & 1) * 8192 + laneA;

        #pragma unroll
        for (int q = 0; q < 4; ++q) {
            const int laneQ = (q >> 1) ? laneQ1 : laneQ0;
            const int np = q & 1;
            if (q == 0 || q == 2) {
                #pragma unroll
                for (int m = 0; m < 8; ++m)
                    af[m] = *(const bf16x8*)(Abase + m * 2048 + laneQ);
            }
            bf16x8 bf0 = *(const bf16x8*)(Bbase + (np * 2) * 2048 + laneQ);
            bf16x8 bf1 = *(const bf16x8*)(Bbase + (np * 2 + 1) * 2048 + laneQ);
            if (hS < NHALF) stage(hS, slotS);
            ++hS; ++slotS; if (slotS >= NSLOT) slotS -= NSLOT;

            __builtin_amdgcn_s_barrier();
            asm volatile("s_waitcnt lgkmcnt(0)" ::: "memory");
            __builtin_amdgcn_sched_barrier(0);
            __builtin_amdgcn_s_setprio(1);
            #pragma unroll
            for (int m = 0; m < 8; ++m) {
                acc[m][np * 2]     = __builtin_amdgcn_mfma_f32_16x16x32_bf16(af[m], bf0, acc[m][np * 2], 0, 0, 0);
                acc[m][np * 2 + 1] = __builtin_amdgcn_mfma_f32_16x16x32_bf16(af[m], bf1, acc[m][np * 2 + 1], 0, 0, 0);
            }
            __builtin_amdgcn_s_setprio(0);
            if (q < 3) __builtin_amdgcn_s_barrier();
        }
        // K-tile boundary: next tile's 4 halves must be resident.
        if (T < 34)       asm volatile("s_waitcnt vmcnt(2)" ::: "memory");
        else if (T == 34) asm volatile("s_waitcnt vmcnt(0)" ::: "memory");
        __builtin_amdgcn_s_barrier();
        __builtin_amdgcn_sched_barrier(0);
        slotC += 4; if (slotC >= NSLOT) slotC -= NSLOT;
    }

    // epilogue: D lane map col = l&15 (pixel), row = (l>>4)*4 + r (oc)
    const int ocb = wm * 128 + ((l >> 4) << 2);
    const int pxb = nt * 256 + wn * 64 + (l & 15);
    #pragma unroll
    for (int i = 0; i < 8; ++i) {
        #pragma unroll
        for (int j = 0; j < 4; ++j) {
            int p = pxb + j * 16;
            if (p < NPIX) {
                float* o = out + ((size_t)(b * NOC + ocb + i * 16)) * NPIX + p;
                o[0]        = acc[i][j][0];
                o[NPIX]     = acc[i][j][1];
                o[2 * NPIX] = acc[i][j][2];
                o[3 * NPIX] = acc[i][j][3];
            }
        }
    }
}

extern "C" void kernel_launch(void* const* d_in, const int* in_sizes, int n_in,
                              void* d_out, int out_size, void* d_ws, size_t ws_size,
                              hipStream_t stream) {
    (void)in_sizes; (void)n_in; (void)out_size; (void)ws_size;
    const float* x   = (const float*)d_in[0];
    const float* rw  = (const float*)d_in[1];
    const float* rb  = (const float*)d_in[2];
    const float* f1w = (const float*)d_in[3];
    const float* f2w = (const float*)d_in[4];
    const float* f2b = (const float*)d_in[5];
    float* out = (float*)d_out;

    char* wsb = (char*)d_ws;
    unsigned short* xbt = (unsigned short*)wsb;
    unsigned short* wa  = (unsigned short*)(wsb + XBT_BYTES);
    float* gap = (float*)(wsb + XBT_BYTES + WA_BYTES);
    float* a2  = (float*)(wsb + XBT_BYTES + WA_BYTES + (size_t)NB * NC * 4);

    hipMemsetAsync(gap, 0, (size_t)NB * NC * 4, stream);
    halo_kernel<<<dim3(32), 256, 0, stream>>>(xbt);
    xpose_kernel<<<dim3(56, 32), 256, 0, stream>>>(x, xbt, gap);
    se_kernel<<<dim3(1), 512, 0, stream>>>(gap, rw, rb, f1w, a2);
    wk_kernel<<<dim3(256, 32), 256, 0, stream>>>(a2, f2w, f2b, wa);
    conv_gemm<<<dim3(416), 512, 0, stream>>>(wa, xbt, out);
}